// Round 4
// baseline (797.571 us; speedup 1.0000x reference)
//
#include <hip/hip_runtime.h>
#include <math.h>

#define T_TOKENS 32768
#define DIM 2048
#define N_EXPERTS 256
#define N_GROUPS 8
#define EPG 32
#define TOPK 8
#define TOPK_GROUPS 4
#define ROUTE_SCALE 2.5f

#define BM 64           // tokens per block; grid 512
#define BK 32           // K-chunk per iteration
#define KITERS (DIM / BK)
#define W_SCALE 256.0f  // pre-scale W so w_lo stays normal in fp16
#define INV_W_SCALE (1.0f / 256.0f)

typedef unsigned short u16;
typedef _Float16 f16x8 __attribute__((ext_vector_type(8)));
typedef float f32x4 __attribute__((ext_vector_type(4)));

__device__ __forceinline__ u16 f16_bits(_Float16 h) {
    union { _Float16 f; u16 u; } c; c.f = h; return c.u;
}

// ---------------------------------------------------------------------------
// Kernel 1: split 256*W (fp32) into fp16 hi/lo planes. 2 MB, L2-resident.
// ---------------------------------------------------------------------------
__global__ __launch_bounds__(256) void convert_w(
    const float* __restrict__ W, u16* __restrict__ Whi, u16* __restrict__ Wlo)
{
    const int i = blockIdx.x * 256 + threadIdx.x;   // 524288 total
    const float x = W[i] * W_SCALE;
    const _Float16 hi = (_Float16)x;
    const _Float16 lo = (_Float16)(x - (float)hi);
    Whi[i] = f16_bits(hi);
    Wlo[i] = f16_bits(lo);
}

// split 8 fp32 (two float4) into fp16 hi/lo fragments — identical arithmetic
// across all rounds (bit-exact logits).
__device__ __forceinline__ void split8(const float4 p, const float4 q,
                                       f16x8* hi, f16x8* lo)
{
    const float v[8] = {p.x, p.y, p.z, p.w, q.x, q.y, q.z, q.w};
    #pragma unroll
    for (int k = 0; k < 8; k++) {
        const _Float16 h = (_Float16)v[k];
        (*hi)[k] = h;
        (*lo)[k] = (_Float16)(v[k] - (float)h);
    }
}

// ---------------------------------------------------------------------------
// Kernel 2: fused  sigmoid(X @ W^T) + bias  ->  group-limited top-k routing.
// Barrier-free K-loop with EXPLICIT register double-buffering (2-phase,
// hand-unrolled, static register sets): compute iter `it` from set A while
// the loads for `it+1` (issued one full phase earlier) land in set B.
// R3's regression was same-iter B-load -> MFMA dependency (L2 latency fully
// exposed every iter); this gives every wait ~1 phase (~500 cyc) of slack.
// ~160 VGPR -> 1 block/CU (2 waves/SIMD): hiding via ILP, not TLP.
// 8 waves (2m x 4n), each 32 tokens x 64 experts. LDS = score buffer only.
// ---------------------------------------------------------------------------
__global__ __launch_bounds__(512, 2) void fused_gate(
    const float* __restrict__ X,
    const u16* __restrict__ Whi, const u16* __restrict__ Wlo,
    const float* __restrict__ bias,
    float* __restrict__ out_w, float* __restrict__ out_i)
{
    __shared__ float Sc[BM * N_EXPERTS];   // 64 KB: biased scores

    const int tid = threadIdx.x;
    const int m0 = blockIdx.x * BM;

    const int lane = tid & 63;
    const int wave = tid >> 6;
    const int wm = wave >> 2;         // 0..1: token half (32 rows)
    const int wn = wave & 3;          // 0..3: expert quarter (64 experts)
    const int l16 = lane & 15;
    const int quad = lane >> 4;

    // A: lane reads 8 fp32 of rows (m0 + wm*32 + l16) and (+16) at k = it*32 + quad*8
    const float* xa0 = X + (size_t)(m0 + wm * 32 + l16) * DIM + quad * 8;
    const float* xa1 = xa0 + 16 * DIM;
    // B: lane reads 8 u16 of W-rows (wn*64 + j*16 + l16) at same k
    const u16* wbh = Whi + (size_t)(wn * 64 + l16) * DIM + quad * 8;
    const u16* wbl = Wlo + (size_t)(wn * 64 + l16) * DIM + quad * 8;

    f32x4 acc[2][4];
    #pragma unroll
    for (int i = 0; i < 2; i++)
        #pragma unroll
        for (int j = 0; j < 4; j++) acc[i][j] = (f32x4){0.f, 0.f, 0.f, 0.f};

    // --- double-buffered operand register sets (static names, rule #20) ---
    float4 aA0, aA1, aA2, aA3;        // raw A, set A
    float4 aB0, aB1, aB2, aB3;        // raw A, set B
    f16x8 bhA[4], blA[4];             // B fragments, set A
    f16x8 bhB[4], blB[4];             // B fragments, set B

    // prologue: it=0 into set A
    aA0 = *(const float4*)(xa0);
    aA1 = *(const float4*)(xa0 + 4);
    aA2 = *(const float4*)(xa1);
    aA3 = *(const float4*)(xa1 + 4);
    #pragma unroll
    for (int j = 0; j < 4; j++) {
        bhA[j] = *(const f16x8*)(wbh + (size_t)j * 16 * DIM);
        blA[j] = *(const f16x8*)(wbl + (size_t)j * 16 * DIM);
    }

    #pragma unroll 1
    for (int it = 0; it < KITERS; it += 2) {
        // ---- phase 0: prefetch it+1 into set B; compute it from set A ----
        {
            const int nxt = (it + 1) * BK;   // it+1 <= 63 always
            aB0 = *(const float4*)(xa0 + nxt);
            aB1 = *(const float4*)(xa0 + nxt + 4);
            aB2 = *(const float4*)(xa1 + nxt);
            aB3 = *(const float4*)(xa1 + nxt + 4);
            #pragma unroll
            for (int j = 0; j < 4; j++) {
                bhB[j] = *(const f16x8*)(wbh + (size_t)j * 16 * DIM + nxt);
                blB[j] = *(const f16x8*)(wbl + (size_t)j * 16 * DIM + nxt);
            }
            f16x8 fah[2], fal[2];
            split8(aA0, aA1, &fah[0], &fal[0]);
            split8(aA2, aA3, &fah[1], &fal[1]);
            #pragma unroll
            for (int i = 0; i < 2; i++)
                #pragma unroll
                for (int j = 0; j < 4; j++) {
                    acc[i][j] = __builtin_amdgcn_mfma_f32_16x16x32_f16(fah[i], bhA[j], acc[i][j], 0, 0, 0);
                    acc[i][j] = __builtin_amdgcn_mfma_f32_16x16x32_f16(fah[i], blA[j], acc[i][j], 0, 0, 0);
                    acc[i][j] = __builtin_amdgcn_mfma_f32_16x16x32_f16(fal[i], bhA[j], acc[i][j], 0, 0, 0);
                }
        }
        // ---- phase 1: prefetch it+2 into set A; compute it+1 from set B ----
        {
            if (it + 2 < KITERS) {
                const int nxt = (it + 2) * BK;
                aA0 = *(const float4*)(xa0 + nxt);
                aA1 = *(const float4*)(xa0 + nxt + 4);
                aA2 = *(const float4*)(xa1 + nxt);
                aA3 = *(const float4*)(xa1 + nxt + 4);
                #pragma unroll
                for (int j = 0; j < 4; j++) {
                    bhA[j] = *(const f16x8*)(wbh + (size_t)j * 16 * DIM + nxt);
                    blA[j] = *(const f16x8*)(wbl + (size_t)j * 16 * DIM + nxt);
                }
            }
            f16x8 fah[2], fal[2];
            split8(aB0, aB1, &fah[0], &fal[0]);
            split8(aB2, aB3, &fah[1], &fal[1]);
            #pragma unroll
            for (int i = 0; i < 2; i++)
                #pragma unroll
                for (int j = 0; j < 4; j++) {
                    acc[i][j] = __builtin_amdgcn_mfma_f32_16x16x32_f16(fah[i], bhB[j], acc[i][j], 0, 0, 0);
                    acc[i][j] = __builtin_amdgcn_mfma_f32_16x16x32_f16(fah[i], blB[j], acc[i][j], 0, 0, 0);
                    acc[i][j] = __builtin_amdgcn_mfma_f32_16x16x32_f16(fal[i], bhB[j], acc[i][j], 0, 0, 0);
                }
        }
    }

    // --- epilogue: biased sigmoid scores -> LDS, then fused routing ---
    float bv[4];
    #pragma unroll
    for (int j = 0; j < 4; j++) bv[j] = bias[wn * 64 + j * 16 + l16];

    #pragma unroll
    for (int i = 0; i < 2; i++)
        #pragma unroll
        for (int j = 0; j < 4; j++)
            #pragma unroll
            for (int r = 0; r < 4; r++) {
                const int trow = wm * 32 + i * 16 + quad * 4 + r;    // 0..63
                const int e = wn * 64 + j * 16 + l16;                // 0..255
                const float logit = acc[i][j][r] * INV_W_SCALE;
                const float s = 1.f / (1.f + expf(-logit));
                Sc[trow * N_EXPERTS + e] = s + bv[j];                // BIASED
            }
    __syncthreads();   // all waves' scores visible to the routing wave

    if (tid < 64) {    // one wave routes 64 tokens; lane-staggered LDS reads
        const float* row = Sc + tid * N_EXPERTS;

        // group score = sum of top-2 biased (matches jax order: m1+m2)
        float gs[N_GROUPS];
        #pragma unroll
        for (int g = 0; g < N_GROUPS; g++) {
            float m1 = -INFINITY, m2 = -INFINITY;
            #pragma unroll
            for (int jj = 0; jj < EPG; jj++) {
                const float v = row[g * EPG + ((tid + jj) & (EPG - 1))];
                if (v > m1) { m2 = m1; m1 = v; }
                else if (v > m2) { m2 = v; }
            }
            gs[g] = m1 + m2;
        }
        // keep top-4 groups (jax tie-break: lower index wins)
        unsigned keep = 0;
        #pragma unroll
        for (int g = 0; g < N_GROUPS; g++) {
            int cnt = 0;
            #pragma unroll
            for (int h = 0; h < N_GROUPS; h++)
                if (gs[h] > gs[g] || (gs[h] == gs[g] && h < g)) cnt++;
            if (cnt < TOPK_GROUPS) keep |= (1u << g);
        }
        // top-8 experts within kept groups; comparator (v desc, idx asc)
        // makes result independent of staggered scan order
        float tv[TOPK]; int ti[TOPK];
        #pragma unroll
        for (int i = 0; i < TOPK; i++) { tv[i] = -INFINITY; ti[i] = 0x7fffffff; }
        for (int g = 0; g < N_GROUPS; g++) {
            if (!(keep & (1u << g))) continue;
            #pragma unroll 4
            for (int jj = 0; jj < EPG; jj++) {
                const int e = g * EPG + ((tid + jj) & (EPG - 1));
                const float v = row[e];
                if (v > tv[TOPK - 1] || (v == tv[TOPK - 1] && e < ti[TOPK - 1])) {
                    float cv = v; int ce = e;
                    #pragma unroll
                    for (int s = 0; s < TOPK; s++) {
                        const bool b = (cv > tv[s]) || (cv == tv[s] && ce < ti[s]);
                        if (b) {
                            const float t1 = tv[s]; tv[s] = cv; cv = t1;
                            const int t2 = ti[s]; ti[s] = ce; ce = t2;
                        }
                    }
                }
            }
        }
        // weights from RAW scores (biased - bias), normalize, scale
        float w[TOPK], sum = 0.f;
        #pragma unroll
        for (int i = 0; i < TOPK; i++) {
            w[i] = row[ti[i]] - bias[ti[i]];
            sum += w[i];
        }
        const float scale = ROUTE_SCALE / fmaxf(sum, 1e-10f);
        const size_t t = (size_t)m0 + tid;
        #pragma unroll
        for (int i = 0; i < TOPK; i++) {
            out_w[t * TOPK + i] = w[i] * scale;
            out_i[t * TOPK + i] = (float)ti[i];
        }
    }
}

extern "C" void kernel_launch(void* const* d_in, const int* in_sizes, int n_in,
                              void* d_out, int out_size, void* d_ws, size_t ws_size,
                              hipStream_t stream)
{
    const float* x = (const float*)d_in[0];     // (T, D)
    const float* w = (const float*)d_in[1];     // (E, D)
    const float* b = (const float*)d_in[2];     // (E,)

    u16* whi = (u16*)d_ws;                      // (E, D) fp16 hi plane, 1 MB
    u16* wlo = whi + (size_t)N_EXPERTS * DIM;   // (E, D) fp16 lo plane, 1 MB

    float* out_w = (float*)d_out;                              // (T, 8)
    float* out_i = (float*)d_out + (size_t)T_TOKENS * TOPK;    // (T, 8) as fp32

    convert_w<<<(N_EXPERTS * DIM) / 256, 256, 0, stream>>>(w, whi, wlo);
    fused_gate<<<T_TOKENS / BM, 512, 0, stream>>>(x, whi, wlo, b, out_w, out_i);
}

// Round 6
// 551.754 us; speedup vs baseline: 1.4455x; 1.4455x over previous
//
#include <hip/hip_runtime.h>
#include <math.h>

#define T_TOKENS 32768
#define DIM 2048
#define N_EXPERTS 256
#define N_GROUPS 8
#define EPG 32
#define TOPK 8
#define TOPK_GROUPS 4
#define ROUTE_SCALE 2.5f

#define BM 64           // tokens per block; grid 512 -> 2 blocks/CU
#define BK 32           // K-chunk per iteration
#define KITERS (DIM / BK)
#define W_SCALE 256.0f  // pre-scale W so w_lo stays normal in fp16
#define INV_W_SCALE (1.0f / 256.0f)

// LDS layout (linear, XOR-swizzled; global_load_lds needs contiguous dest):
//   Abuf fp32 [64 rows][128 B]   @ 0      (8192 B)   swz: p = r*128 + (c ^ ((r&7)<<4))
//   Bhi  fp16 [256 rows][64 B]   @ 8192   (16384 B)  swz: p = r*64  + (c ^ (((r>>1)&3)<<4))
//   Blo  fp16 [256 rows][64 B]   @ 24576  (16384 B)
//   Sc   fp32 [64][256]          @ 0      (65536 B)  epilogue alias
#define A_OFF 0
#define BH_OFF 8192
#define BL_OFF 24576

typedef unsigned short u16;
typedef _Float16 f16x8 __attribute__((ext_vector_type(8)));
typedef float f32x4 __attribute__((ext_vector_type(4)));

__device__ __forceinline__ u16 f16_bits(_Float16 h) {
    union { _Float16 f; u16 u; } c; c.f = h; return c.u;
}

// async global->LDS DMA, 16 B per lane; LDS dest = wave-uniform base + lane*16
__device__ __forceinline__ void gload16(const void* g, void* l) {
    __builtin_amdgcn_global_load_lds(
        (const __attribute__((address_space(1))) void*)g,
        (__attribute__((address_space(3))) void*)l, 16, 0, 0);
}

// ---------------------------------------------------------------------------
// Kernel 1: split 256*W (fp32) into fp16 hi/lo planes. 2 MB, L2-resident.
// ---------------------------------------------------------------------------
__global__ __launch_bounds__(256) void convert_w(
    const float* __restrict__ W, u16* __restrict__ Whi, u16* __restrict__ Wlo)
{
    const int i = blockIdx.x * 256 + threadIdx.x;   // 524288 total
    const float x = W[i] * W_SCALE;
    const _Float16 hi = (_Float16)x;
    const _Float16 lo = (_Float16)(x - (float)hi);
    Whi[i] = f16_bits(hi);
    Wlo[i] = f16_bits(lo);
}

// split 8 fp32 (two float4) into fp16 hi/lo fragments — identical arithmetic
// to all prior rounds (bit-exact logits): same values, same order.
__device__ __forceinline__ void split8(const float4 p, const float4 q,
                                       f16x8* hi, f16x8* lo)
{
    const float v[8] = {p.x, p.y, p.z, p.w, q.x, q.y, q.z, q.w};
    #pragma unroll
    for (int k = 0; k < 8; k++) {
        const _Float16 h = (_Float16)v[k];
        (*hi)[k] = h;
        (*lo)[k] = (_Float16)(v[k] - (float)h);
    }
}

// ---------------------------------------------------------------------------
// Kernel 2: fused  sigmoid(X @ W^T) + bias  ->  group-limited top-k routing.
// m97-recipe staging: global_load_lds DMA (cannot be sunk by the compiler,
// unlike R4's register prefetch), linear LDS with both-sides XOR swizzle
// (pre-swizzled global source + swizzled ds_read addr). A staged as raw fp32,
// split to fp16 hi/lo at fragment-read time (same split8 -> bit-exact).
// Loop: bar(a) -> STAGE(it+1) -> split+MFMA(it) -> bar(b) -> ds_read(it+1).
// 8 waves (2m x 4n); LDS 40 KB staging ∪ 64 KB Sc -> 2 blocks/CU.
// ---------------------------------------------------------------------------
__global__ __launch_bounds__(512, 4) void fused_gate(
    const float* __restrict__ X,
    const u16* __restrict__ Whi, const u16* __restrict__ Wlo,
    const float* __restrict__ bias,
    float* __restrict__ out_w, float* __restrict__ out_i)
{
    __shared__ __align__(16) char smem[65536];
    float* Sc = (float*)smem;         // epilogue alias

    const int tid = threadIdx.x;
    const int m0 = blockIdx.x * BM;
    const int lane = tid & 63;
    const int wave = tid >> 6;
    const int wm = wave >> 2;         // 0..1: token half (32 rows)
    const int wn = wave & 3;          // 0..3: expert quarter (64 experts)
    const int l16 = lane & 15;
    const int quad = lane >> 4;

    // --- DMA assignments (per thread). Each wave owns contiguous 1024B chunks:
    //   A: chunk w -> rows w*8..w*8+7;  B planes: chunks 2w,2w+1 -> rows w*32..+31.
    // Source column is the INVERSE swizzle of the lane's linear LDS slot.
    char* const aDst   = smem + A_OFF  + wave * 1024;
    char* const bhDst0 = smem + BH_OFF + wave * 2048;
    char* const bhDst1 = bhDst0 + 1024;
    char* const blDst0 = smem + BL_OFF + wave * 2048;
    char* const blDst1 = blDst0 + 1024;

    const int aRow  = wave * 8 + (lane >> 3);
    const int aColb = ((lane & 7) ^ (lane >> 3)) << 4;                 // 0..127
    const char* aSrc = (const char*)X + (size_t)(m0 + aRow) * (DIM * 4) + aColb;

    const int bRow0 = wave * 32 + (lane >> 2);
    const int bRow1 = bRow0 + 16;
    const int bColb = ((lane & 3) ^ ((lane >> 3) & 3)) << 4;           // 0..63
    const char* bhSrc0 = (const char*)Whi + (size_t)bRow0 * (DIM * 2) + bColb;
    const char* bhSrc1 = (const char*)Whi + (size_t)bRow1 * (DIM * 2) + bColb;
    const char* blSrc0 = (const char*)Wlo + (size_t)bRow0 * (DIM * 2) + bColb;
    const char* blSrc1 = (const char*)Wlo + (size_t)bRow1 * (DIM * 2) + bColb;

    // --- fragment-read addresses (swizzled; constant across iters) ---
    int aP[2], bP[4];
    #pragma unroll
    for (int i = 0; i < 2; i++) {
        const int r = wm * 32 + i * 16 + l16;
        aP[i] = A_OFF + r * 128 + ((quad * 32) ^ ((r & 7) << 4));
    }
    #pragma unroll
    for (int j = 0; j < 4; j++) {
        const int r = wn * 64 + j * 16 + l16;
        bP[j] = r * 64 + ((quad * 16) ^ (((r >> 1) & 3) << 4));
    }

    f32x4 acc[2][4];
    #pragma unroll
    for (int i = 0; i < 2; i++)
        #pragma unroll
        for (int j = 0; j < 4; j++) acc[i][j] = (f32x4){0.f, 0.f, 0.f, 0.f};

    float4 ra[2][2];
    f16x8 fbh[4], fbl[4];

    // --- prologue: DMA tile 0, wait, read fragments ---
    gload16(aSrc, aDst);
    gload16(bhSrc0, bhDst0);
    gload16(bhSrc1, bhDst1);
    gload16(blSrc0, blDst0);
    gload16(blSrc1, blDst1);
    __syncthreads();
    #pragma unroll
    for (int i = 0; i < 2; i++) {
        ra[i][0] = *(const float4*)(smem + aP[i]);
        ra[i][1] = *(const float4*)(smem + (aP[i] ^ 16));
    }
    #pragma unroll
    for (int j = 0; j < 4; j++) {
        fbh[j] = *(const f16x8*)(smem + BH_OFF + bP[j]);
        fbl[j] = *(const f16x8*)(smem + BL_OFF + bP[j]);
    }

    #pragma unroll 1
    for (int it = 0; it < KITERS; ++it) {
        __syncthreads();   // (a) all waves' frag reads drained -> LDS reusable
        if (it + 1 < KITERS) {   // DMA next tile; latency covered by MFMA below
            const size_t ao = (size_t)(it + 1) * 128;
            const size_t bo = (size_t)(it + 1) * 64;
            gload16(aSrc + ao, aDst);
            gload16(bhSrc0 + bo, bhDst0);
            gload16(bhSrc1 + bo, bhDst1);
            gload16(blSrc0 + bo, blDst0);
            gload16(blSrc1 + bo, blDst1);
        }

        // --- split A (read-side, same arithmetic -> bit-exact) + MFMA ---
        f16x8 fah[2], fal[2];
        split8(ra[0][0], ra[0][1], &fah[0], &fal[0]);
        split8(ra[1][0], ra[1][1], &fah[1], &fal[1]);
        #pragma unroll
        for (int i = 0; i < 2; i++)
            #pragma unroll
            for (int j = 0; j < 4; j++) {
                acc[i][j] = __builtin_amdgcn_mfma_f32_16x16x32_f16(fah[i], fbh[j], acc[i][j], 0, 0, 0);
                acc[i][j] = __builtin_amdgcn_mfma_f32_16x16x32_f16(fah[i], fbl[j], acc[i][j], 0, 0, 0);
                acc[i][j] = __builtin_amdgcn_mfma_f32_16x16x32_f16(fal[i], fbh[j], acc[i][j], 0, 0, 0);
            }

        __syncthreads();   // (b) DMA complete (vmcnt drained by barrier)
        if (it + 1 < KITERS) {   // read next tile's fragments
            #pragma unroll
            for (int i = 0; i < 2; i++) {
                ra[i][0] = *(const float4*)(smem + aP[i]);
                ra[i][1] = *(const float4*)(smem + (aP[i] ^ 16));
            }
            #pragma unroll
            for (int j = 0; j < 4; j++) {
                fbh[j] = *(const f16x8*)(smem + BH_OFF + bP[j]);
                fbl[j] = *(const f16x8*)(smem + BL_OFF + bP[j]);
            }
        }
    }

    // --- epilogue: biased sigmoid scores -> LDS (Sc aliases staging), routing ---
    float bv[4];
    #pragma unroll
    for (int j = 0; j < 4; j++) bv[j] = bias[wn * 64 + j * 16 + l16];

    #pragma unroll
    for (int i = 0; i < 2; i++)
        #pragma unroll
        for (int j = 0; j < 4; j++)
            #pragma unroll
            for (int r = 0; r < 4; r++) {
                const int trow = wm * 32 + i * 16 + quad * 4 + r;    // 0..63
                const int e = wn * 64 + j * 16 + l16;                // 0..255
                const float logit = acc[i][j][r] * INV_W_SCALE;
                const float s = 1.f / (1.f + expf(-logit));
                Sc[trow * N_EXPERTS + e] = s + bv[j];                // BIASED
            }
    __syncthreads();   // all waves' scores visible to the routing wave

    if (tid < 64) {    // one wave routes 64 tokens; lane-staggered LDS reads
        const float* row = Sc + tid * N_EXPERTS;

        // group score = sum of top-2 biased (matches jax order: m1+m2)
        float gs[N_GROUPS];
        #pragma unroll
        for (int g = 0; g < N_GROUPS; g++) {
            float m1 = -INFINITY, m2 = -INFINITY;
            #pragma unroll
            for (int jj = 0; jj < EPG; jj++) {
                const float v = row[g * EPG + ((tid + jj) & (EPG - 1))];
                if (v > m1) { m2 = m1; m1 = v; }
                else if (v > m2) { m2 = v; }
            }
            gs[g] = m1 + m2;
        }
        // keep top-4 groups (jax tie-break: lower index wins)
        unsigned keep = 0;
        #pragma unroll
        for (int g = 0; g < N_GROUPS; g++) {
            int cnt = 0;
            #pragma unroll
            for (int h = 0; h < N_GROUPS; h++)
                if (gs[h] > gs[g] || (gs[h] == gs[g] && h < g)) cnt++;
            if (cnt < TOPK_GROUPS) keep |= (1u << g);
        }
        // top-8 experts within kept groups; comparator (v desc, idx asc)
        // makes result independent of staggered scan order
        float tv[TOPK]; int ti[TOPK];
        #pragma unroll
        for (int i = 0; i < TOPK; i++) { tv[i] = -INFINITY; ti[i] = 0x7fffffff; }
        for (int g = 0; g < N_GROUPS; g++) {
            if (!(keep & (1u << g))) continue;
            #pragma unroll 4
            for (int jj = 0; jj < EPG; jj++) {
                const int e = g * EPG + ((tid + jj) & (EPG - 1));
                const float v = row[e];
                if (v > tv[TOPK - 1] || (v == tv[TOPK - 1] && e < ti[TOPK - 1])) {
                    float cv = v; int ce = e;
                    #pragma unroll
                    for (int s = 0; s < TOPK; s++) {
                        const bool b = (cv > tv[s]) || (cv == tv[s] && ce < ti[s]);
                        if (b) {
                            const float t1 = tv[s]; tv[s] = cv; cv = t1;
                            const int t2 = ti[s]; ti[s] = ce; ce = t2;
                        }
                    }
                }
            }
        }
        // weights from RAW scores (biased - bias), normalize, scale
        float w[TOPK], sum = 0.f;
        #pragma unroll
        for (int i = 0; i < TOPK; i++) {
            w[i] = row[ti[i]] - bias[ti[i]];
            sum += w[i];
        }
        const float scale = ROUTE_SCALE / fmaxf(sum, 1e-10f);
        const size_t t = (size_t)m0 + tid;
        #pragma unroll
        for (int i = 0; i < TOPK; i++) {
            out_w[t * TOPK + i] = w[i] * scale;
            out_i[t * TOPK + i] = (float)ti[i];
        }
    }
}

extern "C" void kernel_launch(void* const* d_in, const int* in_sizes, int n_in,
                              void* d_out, int out_size, void* d_ws, size_t ws_size,
                              hipStream_t stream)
{
    const float* x = (const float*)d_in[0];     // (T, D)
    const float* w = (const float*)d_in[1];     // (E, D)
    const float* b = (const float*)d_in[2];     // (E,)

    u16* whi = (u16*)d_ws;                      // (E, D) fp16 hi plane, 1 MB
    u16* wlo = whi + (size_t)N_EXPERTS * DIM;   // (E, D) fp16 lo plane, 1 MB

    float* out_w = (float*)d_out;                              // (T, 8)
    float* out_i = (float*)d_out + (size_t)T_TOKENS * TOPK;    // (T, 8) as fp32

    convert_w<<<(N_EXPERTS * DIM) / 256, 256, 0, stream>>>(w, whi, wlo);
    fused_gate<<<T_TOKENS / BM, 512, 0, stream>>>(x, whi, wlo, b, out_w, out_i);
}

// Round 7
// 542.667 us; speedup vs baseline: 1.4697x; 1.0167x over previous
//
#include <hip/hip_runtime.h>
#include <math.h>

#define T_TOKENS 32768
#define DIM 2048
#define N_EXPERTS 256
#define N_GROUPS 8
#define EPG 32
#define TOPK 8
#define TOPK_GROUPS 4
#define ROUTE_SCALE 2.5f

#define BM 64           // tokens per block; grid 512 -> 2 blocks/CU
#define BK 32           // K-chunk per iteration
#define KITERS (DIM / BK)
#define W_SCALE 256.0f  // pre-scale W so w_lo stays normal in fp16
#define INV_W_SCALE (1.0f / 256.0f)

// LDS: TWO staging buffers (double-buffer), each 40960 B, linear + XOR-swizzled:
//   per buffer: Abuf fp32 [64r][128B] @ +0     swz: p = r*128 + (c ^ ((r&7)<<4))
//               Bhi  fp16 [256r][64B] @ +8192  swz: p = r*64  + (c ^ (((r>>1)&3)<<4))
//               Blo  fp16 [256r][64B] @ +24576
//   buf0 @ 0, buf1 @ 40960; total 81920 B. 2 blocks x 80KB = 160KB/CU exactly.
//   Sc fp32 [64][256] (65536 B) aliases buf0+part of buf1 in the epilogue.
#define A_OFF 0
#define BH_OFF 8192
#define BL_OFF 24576
#define BUF_STRIDE 40960

typedef unsigned short u16;
typedef _Float16 f16x8 __attribute__((ext_vector_type(8)));
typedef float f32x4 __attribute__((ext_vector_type(4)));

__device__ __forceinline__ u16 f16_bits(_Float16 h) {
    union { _Float16 f; u16 u; } c; c.f = h; return c.u;
}

// async global->LDS DMA, 16 B per lane; LDS dest = wave-uniform base + lane*16
__device__ __forceinline__ void gload16(const void* g, void* l) {
    __builtin_amdgcn_global_load_lds(
        (const __attribute__((address_space(1))) void*)g,
        (__attribute__((address_space(3))) void*)l, 16, 0, 0);
}

// ---------------------------------------------------------------------------
// Kernel 1: split 256*W (fp32) into fp16 hi/lo planes. 2 MB, L2-resident.
// ---------------------------------------------------------------------------
__global__ __launch_bounds__(256) void convert_w(
    const float* __restrict__ W, u16* __restrict__ Whi, u16* __restrict__ Wlo)
{
    const int i = blockIdx.x * 256 + threadIdx.x;   // 524288 total
    const float x = W[i] * W_SCALE;
    const _Float16 hi = (_Float16)x;
    const _Float16 lo = (_Float16)(x - (float)hi);
    Whi[i] = f16_bits(hi);
    Wlo[i] = f16_bits(lo);
}

// split 8 fp32 (two float4) into fp16 hi/lo fragments — identical arithmetic
// to all prior rounds (bit-exact logits): same values, same order.
__device__ __forceinline__ void split8(const float4 p, const float4 q,
                                       f16x8* hi, f16x8* lo)
{
    const float v[8] = {p.x, p.y, p.z, p.w, q.x, q.y, q.z, q.w};
    #pragma unroll
    for (int k = 0; k < 8; k++) {
        const _Float16 h = (_Float16)v[k];
        (*hi)[k] = h;
        (*lo)[k] = (_Float16)(v[k] - (float)h);
    }
}

// ---------------------------------------------------------------------------
// Kernel 2: fused  sigmoid(X @ W^T) + bias  ->  group-limited top-k routing.
// R7: LDS DOUBLE-BUFFER -> ONE barrier per K-step. Phase: issue DMA(t+1)->nxt,
// ds_read+split+MFMA on cur, then __syncthreads() (its vmcnt(0)+lgkm(0) drain
// now sits after a full phase of cover instead of mid-iteration — R6 exposed
// ~500cyc of HBM latency per iter between its two barriers).
// Hazards: tile parity t&1 -> buffer; reads of a buffer complete one barrier
// before its overwrite DMA issues. Numerics bit-exact vs R1-R6.
// 8 waves (2m x 4n); LDS 80 KB -> 2 blocks/CU (160 KB exactly).
// ---------------------------------------------------------------------------
__global__ __launch_bounds__(512, 4) void fused_gate(
    const float* __restrict__ X,
    const u16* __restrict__ Whi, const u16* __restrict__ Wlo,
    const float* __restrict__ bias,
    float* __restrict__ out_w, float* __restrict__ out_i)
{
    __shared__ __align__(16) char smem[81920];
    float* Sc = (float*)smem;         // epilogue alias (65536 B)

    const int tid = threadIdx.x;
    const int m0 = blockIdx.x * BM;
    const int lane = tid & 63;
    const int wave = tid >> 6;
    const int wm = wave >> 2;         // 0..1: token half (32 rows)
    const int wn = wave & 3;          // 0..3: expert quarter (64 experts)
    const int l16 = lane & 15;
    const int quad = lane >> 4;

    // --- DMA assignments (per thread). Each wave owns contiguous 1024B chunks:
    //   A: chunk w -> rows w*8..w*8+7;  B planes: chunks 2w,2w+1 -> rows w*32..+31.
    // Source column is the INVERSE swizzle of the lane's linear LDS slot.
    char* const aDst   = smem + A_OFF  + wave * 1024;
    char* const bhDst0 = smem + BH_OFF + wave * 2048;
    char* const bhDst1 = bhDst0 + 1024;
    char* const blDst0 = smem + BL_OFF + wave * 2048;
    char* const blDst1 = blDst0 + 1024;

    const int aRow  = wave * 8 + (lane >> 3);
    const int aColb = ((lane & 7) ^ (lane >> 3)) << 4;                 // 0..127
    const char* aSrc = (const char*)X + (size_t)(m0 + aRow) * (DIM * 4) + aColb;

    const int bRow0 = wave * 32 + (lane >> 2);
    const int bRow1 = bRow0 + 16;
    const int bColb = ((lane & 3) ^ ((lane >> 3) & 3)) << 4;           // 0..63
    const char* bhSrc0 = (const char*)Whi + (size_t)bRow0 * (DIM * 2) + bColb;
    const char* bhSrc1 = (const char*)Whi + (size_t)bRow1 * (DIM * 2) + bColb;
    const char* blSrc0 = (const char*)Wlo + (size_t)bRow0 * (DIM * 2) + bColb;
    const char* blSrc1 = (const char*)Wlo + (size_t)bRow1 * (DIM * 2) + bColb;

    // --- fragment-read addresses (swizzled; constant across iters) ---
    int aP[2], bP[4];
    #pragma unroll
    for (int i = 0; i < 2; i++) {
        const int r = wm * 32 + i * 16 + l16;
        aP[i] = A_OFF + r * 128 + ((quad * 32) ^ ((r & 7) << 4));
    }
    #pragma unroll
    for (int j = 0; j < 4; j++) {
        const int r = wn * 64 + j * 16 + l16;
        bP[j] = r * 64 + ((quad * 16) ^ (((r >> 1) & 3) << 4));
    }

    f32x4 acc[2][4];
    #pragma unroll
    for (int i = 0; i < 2; i++)
        #pragma unroll
        for (int j = 0; j < 4; j++) acc[i][j] = (f32x4){0.f, 0.f, 0.f, 0.f};

    // --- prologue: DMA tile 0 -> buf0, drain ---
    gload16(aSrc, aDst);
    gload16(bhSrc0, bhDst0);
    gload16(bhSrc1, bhDst1);
    gload16(blSrc0, blDst0);
    gload16(blSrc1, blDst1);
    __syncthreads();

    #pragma unroll 1
    for (int it = 0; it < KITERS; it += 2) {
        // ---- phase 0: DMA tile it+1 -> buf1; compute tile it from buf0 ----
        {
            const size_t ao = (size_t)(it + 1) * 128;   // it+1 <= 63 always
            const size_t bo = (size_t)(it + 1) * 64;
            gload16(aSrc + ao, aDst + BUF_STRIDE);
            gload16(bhSrc0 + bo, bhDst0 + BUF_STRIDE);
            gload16(bhSrc1 + bo, bhDst1 + BUF_STRIDE);
            gload16(blSrc0 + bo, blDst0 + BUF_STRIDE);
            gload16(blSrc1 + bo, blDst1 + BUF_STRIDE);

            float4 ra[2][2];
            f16x8 fbh[4], fbl[4], fah[2], fal[2];
            #pragma unroll
            for (int i = 0; i < 2; i++) {
                ra[i][0] = *(const float4*)(smem + aP[i]);
                ra[i][1] = *(const float4*)(smem + (aP[i] ^ 16));
            }
            #pragma unroll
            for (int j = 0; j < 4; j++) {
                fbh[j] = *(const f16x8*)(smem + BH_OFF + bP[j]);
                fbl[j] = *(const f16x8*)(smem + BL_OFF + bP[j]);
            }
            split8(ra[0][0], ra[0][1], &fah[0], &fal[0]);
            split8(ra[1][0], ra[1][1], &fah[1], &fal[1]);
            #pragma unroll
            for (int i = 0; i < 2; i++)
                #pragma unroll
                for (int j = 0; j < 4; j++) {
                    acc[i][j] = __builtin_amdgcn_mfma_f32_16x16x32_f16(fah[i], fbh[j], acc[i][j], 0, 0, 0);
                    acc[i][j] = __builtin_amdgcn_mfma_f32_16x16x32_f16(fah[i], fbl[j], acc[i][j], 0, 0, 0);
                    acc[i][j] = __builtin_amdgcn_mfma_f32_16x16x32_f16(fal[i], fbh[j], acc[i][j], 0, 0, 0);
                }
            __syncthreads();   // drains this phase's DMA (vmcnt0) + reads (lgkm0)
        }
        // ---- phase 1: DMA tile it+2 -> buf0; compute tile it+1 from buf1 ----
        {
            if (it + 2 < KITERS) {
                const size_t ao = (size_t)(it + 2) * 128;
                const size_t bo = (size_t)(it + 2) * 64;
                gload16(aSrc + ao, aDst);
                gload16(bhSrc0 + bo, bhDst0);
                gload16(bhSrc1 + bo, bhDst1);
                gload16(blSrc0 + bo, blDst0);
                gload16(blSrc1 + bo, blDst1);
            }
            float4 ra[2][2];
            f16x8 fbh[4], fbl[4], fah[2], fal[2];
            #pragma unroll
            for (int i = 0; i < 2; i++) {
                ra[i][0] = *(const float4*)(smem + BUF_STRIDE + aP[i]);
                ra[i][1] = *(const float4*)(smem + BUF_STRIDE + (aP[i] ^ 16));
            }
            #pragma unroll
            for (int j = 0; j < 4; j++) {
                fbh[j] = *(const f16x8*)(smem + BUF_STRIDE + BH_OFF + bP[j]);
                fbl[j] = *(const f16x8*)(smem + BUF_STRIDE + BL_OFF + bP[j]);
            }
            split8(ra[0][0], ra[0][1], &fah[0], &fal[0]);
            split8(ra[1][0], ra[1][1], &fah[1], &fal[1]);
            #pragma unroll
            for (int i = 0; i < 2; i++)
                #pragma unroll
                for (int j = 0; j < 4; j++) {
                    acc[i][j] = __builtin_amdgcn_mfma_f32_16x16x32_f16(fah[i], fbh[j], acc[i][j], 0, 0, 0);
                    acc[i][j] = __builtin_amdgcn_mfma_f32_16x16x32_f16(fah[i], fbl[j], acc[i][j], 0, 0, 0);
                    acc[i][j] = __builtin_amdgcn_mfma_f32_16x16x32_f16(fal[i], fbh[j], acc[i][j], 0, 0, 0);
                }
            __syncthreads();
        }
    }

    // --- epilogue: biased sigmoid scores -> LDS (Sc alias), fused routing ---
    float bv[4];
    #pragma unroll
    for (int j = 0; j < 4; j++) bv[j] = bias[wn * 64 + j * 16 + l16];

    #pragma unroll
    for (int i = 0; i < 2; i++)
        #pragma unroll
        for (int j = 0; j < 4; j++)
            #pragma unroll
            for (int r = 0; r < 4; r++) {
                const int trow = wm * 32 + i * 16 + quad * 4 + r;    // 0..63
                const int e = wn * 64 + j * 16 + l16;                // 0..255
                const float logit = acc[i][j][r] * INV_W_SCALE;
                const float s = 1.f / (1.f + expf(-logit));
                Sc[trow * N_EXPERTS + e] = s + bv[j];                // BIASED
            }
    __syncthreads();   // all waves' scores visible to the routing wave

    if (tid < 64) {    // one wave routes 64 tokens; lane-staggered LDS reads
        const float* row = Sc + tid * N_EXPERTS;

        // group score = sum of top-2 biased (matches jax order: m1+m2)
        float gs[N_GROUPS];
        #pragma unroll
        for (int g = 0; g < N_GROUPS; g++) {
            float m1 = -INFINITY, m2 = -INFINITY;
            #pragma unroll
            for (int jj = 0; jj < EPG; jj++) {
                const float v = row[g * EPG + ((tid + jj) & (EPG - 1))];
                if (v > m1) { m2 = m1; m1 = v; }
                else if (v > m2) { m2 = v; }
            }
            gs[g] = m1 + m2;
        }
        // keep top-4 groups (jax tie-break: lower index wins)
        unsigned keep = 0;
        #pragma unroll
        for (int g = 0; g < N_GROUPS; g++) {
            int cnt = 0;
            #pragma unroll
            for (int h = 0; h < N_GROUPS; h++)
                if (gs[h] > gs[g] || (gs[h] == gs[g] && h < g)) cnt++;
            if (cnt < TOPK_GROUPS) keep |= (1u << g);
        }
        // top-8 experts within kept groups; comparator (v desc, idx asc)
        // makes result independent of staggered scan order
        float tv[TOPK]; int ti[TOPK];
        #pragma unroll
        for (int i = 0; i < TOPK; i++) { tv[i] = -INFINITY; ti[i] = 0x7fffffff; }
        for (int g = 0; g < N_GROUPS; g++) {
            if (!(keep & (1u << g))) continue;
            #pragma unroll 4
            for (int jj = 0; jj < EPG; jj++) {
                const int e = g * EPG + ((tid + jj) & (EPG - 1));
                const float v = row[e];
                if (v > tv[TOPK - 1] || (v == tv[TOPK - 1] && e < ti[TOPK - 1])) {
                    float cv = v; int ce = e;
                    #pragma unroll
                    for (int s = 0; s < TOPK; s++) {
                        const bool b = (cv > tv[s]) || (cv == tv[s] && ce < ti[s]);
                        if (b) {
                            const float t1 = tv[s]; tv[s] = cv; cv = t1;
                            const int t2 = ti[s]; ti[s] = ce; ce = t2;
                        }
                    }
                }
            }
        }
        // weights from RAW scores (biased - bias), normalize, scale
        float w[TOPK], sum = 0.f;
        #pragma unroll
        for (int i = 0; i < TOPK; i++) {
            w[i] = row[ti[i]] - bias[ti[i]];
            sum += w[i];
        }
        const float scale = ROUTE_SCALE / fmaxf(sum, 1e-10f);
        const size_t t = (size_t)m0 + tid;
        #pragma unroll
        for (int i = 0; i < TOPK; i++) {
            out_w[t * TOPK + i] = w[i] * scale;
            out_i[t * TOPK + i] = (float)ti[i];
        }
    }
}

extern "C" void kernel_launch(void* const* d_in, const int* in_sizes, int n_in,
                              void* d_out, int out_size, void* d_ws, size_t ws_size,
                              hipStream_t stream)
{
    const float* x = (const float*)d_in[0];     // (T, D)
    const float* w = (const float*)d_in[1];     // (E, D)
    const float* b = (const float*)d_in[2];     // (E,)

    u16* whi = (u16*)d_ws;                      // (E, D) fp16 hi plane, 1 MB
    u16* wlo = whi + (size_t)N_EXPERTS * DIM;   // (E, D) fp16 lo plane, 1 MB

    float* out_w = (float*)d_out;                              // (T, 8)
    float* out_i = (float*)d_out + (size_t)T_TOKENS * TOPK;    // (T, 8) as fp32

    convert_w<<<(N_EXPERTS * DIM) / 256, 256, 0, stream>>>(w, whi, wlo);
    fused_gate<<<T_TOKENS / BM, 512, 0, stream>>>(x, whi, wlo, b, out_w, out_i);
}